// Round 2
// baseline (390.137 us; speedup 1.0000x reference)
//
#include <hip/hip_runtime.h>
#include <hip/hip_bf16.h>

typedef unsigned short ushort_t;

__device__ __forceinline__ float bf2f(ushort_t u) {
    union { unsigned int i; float f; } v; v.i = ((unsigned int)u) << 16; return v.f;
}
__device__ __forceinline__ ushort_t f2bf(float f) {
    union { float f; unsigned int i; } v; v.f = f;
    unsigned int r = v.i + 0x7FFFu + ((v.i >> 16) & 1u);   // round-to-nearest-even
    return (ushort_t)(r >> 16);
}

// Problem constants: B=16, C=64, H=W=80, s=2, Hs=Ws=160. All tensors fp32.
#define BB 16
#define CC 64
#define HH 80
#define WW 80
#define HS 160
#define WS 160
#define HW (HH*WW)          // 6400

// ---------------------------------------------------------------------------
// Kernel A0: parameter prep (fp32): wmat[12][64], wbias[12], cwT[c][o], bnA/bnB
// ---------------------------------------------------------------------------
__global__ void prep_params(const float* __restrict__ offset_w,
                            const float* __restrict__ offset_b,
                            const float* __restrict__ mask_w,
                            const float* __restrict__ mask_b,
                            const float* __restrict__ conv_w,
                            const float* __restrict__ gamma,
                            const float* __restrict__ beta,
                            const float* __restrict__ mean,
                            const float* __restrict__ var,
                            float* __restrict__ wmat, float* __restrict__ wbias,
                            float* __restrict__ cwT,
                            float* __restrict__ bnA, float* __restrict__ bnB) {
    int t = threadIdx.x;
    for (int i = t; i < 12 * 64; i += 256) {
        int ch = i >> 6, c = i & 63;
        wmat[i] = ch < 8 ? offset_w[ch * 64 + c] : mask_w[(ch - 8) * 64 + c];
    }
    if (t < 12) wbias[t] = t < 8 ? offset_b[t] : mask_b[t - 8];
    for (int i = t; i < 64 * 64; i += 256) {
        int c = i >> 6, o = i & 63;
        cwT[i] = conv_w[o * 64 + c];                // cwT[c][o]
    }
    if (t < 64) {
        float A = gamma[t] * rsqrtf(var[t] + 1e-5f);
        bnA[t] = A;
        bnB[t] = beta[t] - mean[t] * A;
    }
}

// ---------------------------------------------------------------------------
// Kernel A1: transpose x[B,C,H,W] fp32 -> xT[B,H*W,C] bf16 (LDS tiled)
// ---------------------------------------------------------------------------
__global__ __launch_bounds__(256) void transpose_x(const float* __restrict__ x,
                                                   ushort_t* __restrict__ xT) {
    __shared__ ushort_t tile[64 * 65];
    int b = blockIdx.y;
    int hw0 = blockIdx.x * 64;
    int t = threadIdx.x;
#pragma unroll
    for (int k = 0; k < 16; ++k) {
        int e = k * 256 + t;
        int c = e >> 6, j = e & 63;
        tile[c * 65 + j] = f2bf(x[(b * CC + c) * HW + hw0 + j]);   // j contiguous
    }
    __syncthreads();
#pragma unroll
    for (int k = 0; k < 16; ++k) {
        int e = k * 256 + t;
        int j = e >> 6, c = e & 63;
        xT[((b * HW) + hw0 + j) * CC + c] = tile[c * 65 + j];      // c contiguous
    }
}

// ---------------------------------------------------------------------------
// Kernel A2: low-res 1x1 conv from ORIGINAL fp32 x (full precision offsets):
// offs[B*H*W][12] = {ox[4], oy[4], sigmoid(mask)[4]}
// ---------------------------------------------------------------------------
__global__ __launch_bounds__(256) void lowres_conv(const float* __restrict__ x,
                                                   const float* __restrict__ wmat,
                                                   const float* __restrict__ wbias,
                                                   float* __restrict__ offs) {
    __shared__ float sX[64 * 65];   // [px][c]
    int t = threadIdx.x;
    int pxbase = blockIdx.x * 64;       // HW divisible by 64 -> tile within one b
    int b = pxbase / HW;
    int hw0 = pxbase - b * HW;
#pragma unroll
    for (int k = 0; k < 16; ++k) {
        int e = k * 256 + t;
        int c = e >> 6, j = e & 63;
        sX[j * 65 + c] = x[(b * CC + c) * HW + hw0 + j];   // j contiguous
    }
    __syncthreads();
    int px = t & 63;
    int chunk = __builtin_amdgcn_readfirstlane(t >> 6);   // 0..3 -> 3 channels each
    int ch0 = chunk * 3;
    const float* w0 = wmat + (ch0 + 0) * 64;
    const float* w1 = wmat + (ch0 + 1) * 64;
    const float* w2 = wmat + (ch0 + 2) * 64;
    float a0 = 0.f, a1 = 0.f, a2 = 0.f;
#pragma unroll 4
    for (int c = 0; c < 64; ++c) {
        float v = sX[px * 65 + c];
        a0 += v * w0[c];
        a1 += v * w1[c];
        a2 += v * w2[c];
    }
    a0 += wbias[ch0 + 0];
    a1 += wbias[ch0 + 1];
    a2 += wbias[ch0 + 2];
    if (ch0 + 0 >= 8) a0 = 1.0f / (1.0f + __expf(-a0));
    if (ch0 + 1 >= 8) a1 = 1.0f / (1.0f + __expf(-a1));
    if (ch0 + 2 >= 8) a2 = 1.0f / (1.0f + __expf(-a2));
    float* op = offs + (pxbase + px) * 12;
    op[ch0 + 0] = a0;
    op[ch0 + 1] = a1;
    op[ch0 + 2] = a2;
}

// ---------------------------------------------------------------------------
// tap builder: composes grid_sample bilinear (on 160-grid, zero pad) with
// 2x bilinear upsample (on 80-grid, edge clamp). 4 entries, middle two merged.
// ---------------------------------------------------------------------------
__device__ __forceinline__ void build_taps(int i0, float w1, int idx[4], float wt[4]) {
#pragma unroll
    for (int j = 0; j < 2; ++j) {
        int u = i0 + j;
        float gw = j ? w1 : (1.0f - w1);
        if (u < 0 || u >= 160) {
            idx[2 * j] = 0; wt[2 * j] = 0.f;
            idx[2 * j + 1] = 0; wt[2 * j + 1] = 0.f;
            continue;
        }
        float cc = (float)u * 0.5f - 0.25f;
        cc = fminf(fmaxf(cc, 0.0f), 79.0f);
        float fc = floorf(cc);
        int c0 = (int)fc;
        float wv = cc - fc;
        int c1 = c0 + 1; if (c1 > 79) c1 = 79;
        idx[2 * j] = c0;     wt[2 * j] = gw * (1.0f - wv);
        idx[2 * j + 1] = c1; wt[2 * j + 1] = gw * wv;
    }
    if (idx[2] == idx[1]) { wt[1] += wt[2]; wt[2] = 0.f; }   // common overlap
}

// ---------------------------------------------------------------------------
// Main kernel: block = (wseg, ho, b); 64 output pixels per block.
// Phase 1: sample+mask -> LDS sOut[c][p]. Phase 2: 64x64 conv + BN + SiLU.
// ---------------------------------------------------------------------------
__global__ __launch_bounds__(256) void dysample_main(const ushort_t* __restrict__ xT,
                                                     const float* __restrict__ offs,
                                                     const float* __restrict__ cwT,
                                                     const float* __restrict__ bnA,
                                                     const float* __restrict__ bnB,
                                                     float* __restrict__ out) {
    __shared__ float sOut[64 * 65];   // [c][p], stride 65 -> conflict-free
    int wseg = blockIdx.x, ho = blockIdx.y, b = blockIdx.z;
    int wbase = wseg * 64;
    int t = threadIdx.x;
    int lane = t & 63;
    int wave = __builtin_amdgcn_readfirstlane(t >> 6);

    int h = ho >> 1, r1 = ho & 1;
    float gyb = -1.0f + (float)ho * (2.0f / 159.0f);
    const ushort_t* xb = xT + (long)b * HW * CC;

    for (int i = 0; i < 16; ++i) {
        int px = wave * 16 + i;
        int wo = wbase + px;
        if (wo >= WS) break;                 // wave-uniform
        int w = wo >> 1;
        int r = r1 * 2 + (wo & 1);
        const float* op = offs + ((b * HW) + h * WW + w) * 12;
        float ox = op[r], oy = op[4 + r], mk = op[8 + r];
        float gx = -1.0f + (float)wo * (2.0f / 159.0f) + ox;
        float gy = gyb + oy;
        float ix = (gx + 1.0f) * 80.0f - 0.5f;   // ((g+1)*160 - 1) * 0.5
        float iy = (gy + 1.0f) * 80.0f - 0.5f;
        float fx = floorf(ix); int ix0 = (int)fx; float wx1 = ix - fx;
        float fy = floorf(iy); int iy0 = (int)fy; float wy1 = iy - fy;
        int rI[4], cI[4];
        float rW[4], cW[4];
        build_taps(iy0, wy1, rI, rW);
        build_taps(ix0, wx1, cI, cW);
        float acc = 0.f;
#pragma unroll
        for (int a = 0; a < 4; ++a) {
            float rw = rW[a];
            if (rw == 0.f) continue;         // wave-uniform skip
            const ushort_t* xr = xb + rI[a] * (WW * CC);
#pragma unroll
            for (int bb = 0; bb < 4; ++bb) {
                float wgt = rw * cW[bb];
                if (wgt == 0.f) continue;
                acc += wgt * bf2f(xr[cI[bb] * CC + lane]);   // coalesced 128B
            }
        }
        sOut[lane * 65 + px] = acc * mk;
    }
    __syncthreads();

    // Phase 2: y[p][o] = sum_c cwT[c][o] * sOut[c][p], o-chunk per wave
    int p = lane;
    int chunk = wave;                       // 16 output channels per wave
    float acc2[16];
#pragma unroll
    for (int j = 0; j < 16; ++j) acc2[j] = 0.f;
#pragma unroll 4
    for (int c = 0; c < 64; ++c) {
        float v = sOut[c * 65 + p];
        const float* wrow = cwT + c * 64 + chunk * 16;   // uniform -> s_load
#pragma unroll
        for (int j = 0; j < 16; ++j) acc2[j] += v * wrow[j];
    }
    int wo = wbase + p;
    if (wo < WS) {
        long outbase = (((long)b * CC) * HS + ho) * WS + wo;
#pragma unroll
        for (int j = 0; j < 16; ++j) {
            int o = chunk * 16 + j;
            float yv = acc2[j] * bnA[o] + bnB[o];
            float si = yv * (1.0f / (1.0f + __expf(-yv)));
            out[outbase + (long)o * (HS * WS)] = si;
        }
    }
}

// ---------------------------------------------------------------------------
extern "C" void kernel_launch(void* const* d_in, const int* in_sizes, int n_in,
                              void* d_out, int out_size, void* d_ws, size_t ws_size,
                              hipStream_t stream) {
    const float* x        = (const float*)d_in[0];
    const float* offset_w = (const float*)d_in[1];
    const float* offset_b = (const float*)d_in[2];
    const float* mask_w   = (const float*)d_in[3];
    const float* mask_b   = (const float*)d_in[4];
    const float* conv_w   = (const float*)d_in[5];
    const float* bn_gamma = (const float*)d_in[6];
    const float* bn_beta  = (const float*)d_in[7];
    const float* bn_mean  = (const float*)d_in[8];
    const float* bn_var   = (const float*)d_in[9];
    // d_in[10] = scale (always 2) — compile-time constant here.

    char* ws = (char*)d_ws;
    size_t off = 0;
    ushort_t* xT = (ushort_t*)(ws + off); off += (size_t)BB * HW * CC * 2;      // 13,107,200
    float* offs  = (float*)(ws + off);    off += (size_t)BB * HW * 12 * 4;      //  4,915,200
    float* cwT   = (float*)(ws + off);    off += 64 * 64 * 4;
    float* wmat  = (float*)(ws + off);    off += 12 * 64 * 4;
    float* wbias = (float*)(ws + off);    off += 64;
    float* bnA   = (float*)(ws + off);    off += 64 * 4;
    float* bnB   = (float*)(ws + off);    off += 64 * 4;

    prep_params<<<1, 256, 0, stream>>>(offset_w, offset_b, mask_w, mask_b, conv_w,
                                       bn_gamma, bn_beta, bn_mean, bn_var,
                                       wmat, wbias, cwT, bnA, bnB);
    transpose_x<<<dim3(HW / 64, BB), 256, 0, stream>>>(x, xT);
    lowres_conv<<<(BB * HW) / 64, 256, 0, stream>>>(x, wmat, wbias, offs);
    dysample_main<<<dim3(3, HS, BB), 256, 0, stream>>>(xT, offs, cwT, bnA, bnB,
                                                       (float*)d_out);
}

// Round 3
// 189.864 us; speedup vs baseline: 2.0548x; 2.0548x over previous
//
#include <hip/hip_runtime.h>

typedef unsigned short ushort_t;
typedef __attribute__((ext_vector_type(8))) short bf16x8;
typedef __attribute__((ext_vector_type(4))) float f32x4;

__device__ __forceinline__ float bf2f(ushort_t u) {
    union { unsigned int i; float f; } v; v.i = ((unsigned int)u) << 16; return v.f;
}
__device__ __forceinline__ ushort_t f2bf(float f) {
    union { float f; unsigned int i; } v; v.f = f;
    unsigned int r = v.i + 0x7FFFu + ((v.i >> 16) & 1u);   // RNE
    return (ushort_t)(r >> 16);
}

// Problem constants: B=16, C=64, H=W=80, s=2, Hs=Ws=160. fp32 I/O.
#define BB 16
#define CC 64
#define HH 80
#define WW 80
#define HS 160
#define WS 160
#define HW (HH*WW)          // 6400
#define HWS (HS*WS)         // 25600

// ---------------------------------------------------------------------------
// prep_params: wmat[12][64], wbias[12], cwBf[cout][cin] bf16, bnA/bnB fp32
// ---------------------------------------------------------------------------
__global__ void prep_params(const float* __restrict__ offset_w,
                            const float* __restrict__ offset_b,
                            const float* __restrict__ mask_w,
                            const float* __restrict__ mask_b,
                            const float* __restrict__ conv_w,
                            const float* __restrict__ gamma,
                            const float* __restrict__ beta,
                            const float* __restrict__ mean,
                            const float* __restrict__ var,
                            float* __restrict__ wmat, float* __restrict__ wbias,
                            ushort_t* __restrict__ cwBf,
                            float* __restrict__ bnA, float* __restrict__ bnB) {
    int t = threadIdx.x;
    for (int i = t; i < 12 * 64; i += 256) {
        int ch = i >> 6, c = i & 63;
        wmat[i] = ch < 8 ? offset_w[ch * 64 + c] : mask_w[(ch - 8) * 64 + c];
    }
    if (t < 12) wbias[t] = t < 8 ? offset_b[t] : mask_b[t - 8];
    for (int i = t; i < 64 * 64; i += 256) cwBf[i] = f2bf(conv_w[i]);  // [o][c] row-major
    if (t < 64) {
        float A = gamma[t] * rsqrtf(var[t] + 1e-5f);
        bnA[t] = A;
        bnB[t] = beta[t] - mean[t] * A;
    }
}

// ---------------------------------------------------------------------------
// prep_x: fused transpose (x fp32 -> xT bf16 channel-last) + low-res 12-ch conv
// ---------------------------------------------------------------------------
__global__ __launch_bounds__(256) void prep_x(const float* __restrict__ x,
                                              const float* __restrict__ wmat,
                                              const float* __restrict__ wbias,
                                              ushort_t* __restrict__ xT,
                                              float* __restrict__ offs) {
    __shared__ float sX[64 * 65];   // [px][c]
    int t = threadIdx.x;
    int tile = blockIdx.x;          // 0..1599
    int b = tile / 100;             // 100 tiles of 64 px per image
    int hw0 = (tile - b * 100) * 64;
#pragma unroll
    for (int k = 0; k < 16; ++k) {
        int e = k * 256 + t;
        int c = e >> 6, j = e & 63;
        sX[j * 65 + c] = x[((b * CC + c) * HW) + hw0 + j];   // j contiguous: coalesced
    }
    __syncthreads();
    // transpose write: c contiguous across lanes
#pragma unroll
    for (int k = 0; k < 16; ++k) {
        int e = k * 256 + t;
        int j = e >> 6, c = e & 63;
        xT[((size_t)(b * HW) + hw0 + j) * CC + c] = f2bf(sX[j * 65 + c]);
    }
    // 12-channel conv: lane=px, 4 waves x 3 channels
    int px = t & 63;
    int chunk = __builtin_amdgcn_readfirstlane(t >> 6);
    int ch0 = chunk * 3;
    const float* w0 = wmat + (ch0 + 0) * 64;
    const float* w1 = wmat + (ch0 + 1) * 64;
    const float* w2 = wmat + (ch0 + 2) * 64;
    float a0 = 0.f, a1 = 0.f, a2 = 0.f;
#pragma unroll 4
    for (int c = 0; c < 64; ++c) {
        float v = sX[px * 65 + c];
        a0 += v * w0[c];
        a1 += v * w1[c];
        a2 += v * w2[c];
    }
    a0 += wbias[ch0 + 0];
    a1 += wbias[ch0 + 1];
    a2 += wbias[ch0 + 2];
    if (ch0 + 0 >= 8) a0 = 1.0f / (1.0f + __expf(-a0));
    if (ch0 + 1 >= 8) a1 = 1.0f / (1.0f + __expf(-a1));
    if (ch0 + 2 >= 8) a2 = 1.0f / (1.0f + __expf(-a2));
    float* op = offs + (size_t)(b * HW + hw0 + px) * 12;
    op[ch0 + 0] = a0;
    op[ch0 + 1] = a1;
    op[ch0 + 2] = a2;
}

// ---------------------------------------------------------------------------
// axis taps: compose grid_sample (160-grid, zero pad) with 2x bilinear
// upsample (80-grid, edge clamp) -> 3-wide window [base, base+2], base∈[0,77].
// ---------------------------------------------------------------------------
#define ACC3(w, k, val) { float _v = (val); \
    w[0] += (k) == 0 ? _v : 0.f; w[1] += (k) == 1 ? _v : 0.f; w[2] += (k) == 2 ? _v : 0.f; }

__device__ __forceinline__ void axis_taps(float pos, int& base, float w[3]) {
    float f = floorf(pos); int u0 = (int)f; float g1 = pos - f;
    w[0] = w[1] = w[2] = 0.f;
    bool v0 = (u0 >= 0) & (u0 < 160);
    bool v1 = (u0 + 1 >= 0) & (u0 + 1 < 160);
    float cc0 = 0.f, cc1 = 0.f; int ca0 = 0, ca1 = 0;
    if (v0) { cc0 = fminf(fmaxf((float)u0 * 0.5f - 0.25f, 0.f), 79.f); ca0 = (int)floorf(cc0); }
    if (v1) { cc1 = fminf(fmaxf((float)(u0 + 1) * 0.5f - 0.25f, 0.f), 79.f); ca1 = (int)floorf(cc1); }
    int first = v0 ? ca0 : (v1 ? ca1 : 0);
    base = min(first, 77);
    if (v0) {
        float wv = cc0 - (float)ca0; int c1 = min(ca0 + 1, 79);
        int k0 = ca0 - base, k1 = c1 - base;
        ACC3(w, k0, (1.f - g1) * (1.f - wv));
        ACC3(w, k1, (1.f - g1) * wv);
    }
    if (v1) {
        float wv = cc1 - (float)ca1; int c1 = min(ca1 + 1, 79);
        int k0 = ca1 - base, k1 = c1 - base;
        ACC3(w, k0, g1 * (1.f - wv));
        ACC3(w, k1, g1 * wv);
    }
}

// ---------------------------------------------------------------------------
// main: 64 output pixels per block (flat tiling, no dead slots).
// Phase 0: wave 0 builds taps for the 64 px -> LDS (8 dwords/px).
// Phase 1: lane=cin, wave handles 16 px; 9 loads + 12 FMA each -> S bf16.
// Phase 2: MFMA 16x16x32 bf16: D[cout][px] = W[cout][cin] * S[cin][px]; BN+SiLU.
// ---------------------------------------------------------------------------
__global__ __launch_bounds__(256) void dysample_main(const ushort_t* __restrict__ xT,
                                                     const float* __restrict__ offs,
                                                     const ushort_t* __restrict__ cwBf,
                                                     const float* __restrict__ bnA,
                                                     const float* __restrict__ bnB,
                                                     float* __restrict__ out) {
    __shared__ float sTap[64 * 8];       // bits(cb|rb<<16), cw0..2, rw0..2, mask
    __shared__ ushort_t S[64 * 72];      // [px][cin], stride 72 (16B-aligned rows)
    int t = threadIdx.x;
    int lane = t & 63;
    int wave = __builtin_amdgcn_readfirstlane(t >> 6);
    int quad = lane >> 4, nrow = lane & 15;
    int b = blockIdx.y;
    int pix0 = blockIdx.x * 64;

    // preload A-fragments (conv weights, bf16) + BN params for this wave's couts
    const ushort_t* wp = cwBf + (wave * 16 + nrow) * 64 + quad * 8;
    bf16x8 af0 = *(const bf16x8*)(wp);
    bf16x8 af1 = *(const bf16x8*)(wp + 32);
    int coutD = wave * 16 + quad * 4;
    float bnAv[4], bnBv[4];
#pragma unroll
    for (int j = 0; j < 4; ++j) { bnAv[j] = bnA[coutD + j]; bnBv[j] = bnB[coutD + j]; }

    // ---- phase 0: taps (wave 0 only, lane = px)
    if (t < 64) {
        int pix = pix0 + t;
        int ho = pix / WS, wo = pix - ho * WS;
        int h = ho >> 1, w = wo >> 1, r = ((ho & 1) << 1) | (wo & 1);
        const float* op = offs + (size_t)((b * HW) + h * WW + w) * 12;
        float ox = op[r], oy = op[4 + r], mk = op[8 + r];
        // ix = ((gx+1)*160-1)*0.5 with gx = -1 + wo*2/159 + ox
        float ix = (float)wo * (160.0f / 159.0f) - 0.5f + 80.0f * ox;
        float iy = (float)ho * (160.0f / 159.0f) - 0.5f + 80.0f * oy;
        int cb, rb; float cw[3], rw[3];
        axis_taps(ix, cb, cw);
        axis_taps(iy, rb, rw);
        sTap[t * 8 + 0] = __int_as_float(cb | (rb << 16));
        sTap[t * 8 + 1] = cw[0]; sTap[t * 8 + 2] = cw[1]; sTap[t * 8 + 3] = cw[2];
        sTap[t * 8 + 4] = rw[0]; sTap[t * 8 + 5] = rw[1]; sTap[t * 8 + 6] = rw[2];
        sTap[t * 8 + 7] = mk;
    }
    __syncthreads();

    // ---- phase 1: sample 16 px per wave, lane = input channel
    const ushort_t* xb = xT + (size_t)b * HW * CC;
#pragma unroll 2
    for (int i = 0; i < 16; ++i) {
        int px = wave * 16 + i;
        f32x4 t0 = *(const f32x4*)(sTap + px * 8);       // broadcast reads
        f32x4 t1 = *(const f32x4*)(sTap + px * 8 + 4);
        int bits = __float_as_int(t0.x);
        int cb = bits & 0xffff, rb = bits >> 16;
        const ushort_t* p0 = xb + (rb * WW + cb) * CC + lane;
        float acc = 0.f;
#pragma unroll
        for (int rr = 0; rr < 3; ++rr) {
            const ushort_t* pr = p0 + rr * (WW * CC);
            float v0 = bf2f(pr[0]);
            float v1 = bf2f(pr[64]);
            float v2 = bf2f(pr[128]);
            float rowa = t0.y * v0 + t0.z * v1 + t0.w * v2;
            float rwv = (rr == 0) ? t1.x : ((rr == 1) ? t1.y : t1.z);
            acc += rwv * rowa;
        }
        S[px * 72 + lane] = f2bf(acc * t1.w);
    }
    __syncthreads();

    // ---- phase 2: D[cout][px] via MFMA; wave = cout tile
    f32x4 acc4[4];
#pragma unroll
    for (int n = 0; n < 4; ++n) acc4[n] = (f32x4){0.f, 0.f, 0.f, 0.f};
#pragma unroll
    for (int n = 0; n < 4; ++n) {
        const ushort_t* sp = S + (n * 16 + nrow) * 72 + quad * 8;
        bf16x8 b0 = *(const bf16x8*)(sp);        // k = 0..31
        bf16x8 b1 = *(const bf16x8*)(sp + 32);   // k = 32..63
        acc4[n] = __builtin_amdgcn_mfma_f32_16x16x32_bf16(af0, b0, acc4[n], 0, 0, 0);
        acc4[n] = __builtin_amdgcn_mfma_f32_16x16x32_bf16(af1, b1, acc4[n], 0, 0, 0);
    }

    // epilogue: BN + SiLU + store (16 px contiguous per quad-group)
    size_t ob = (size_t)b * CC * HWS;
#pragma unroll
    for (int n = 0; n < 4; ++n) {
        int pix = pix0 + n * 16 + nrow;
#pragma unroll
        for (int j = 0; j < 4; ++j) {
            float y = acc4[n][j] * bnAv[j] + bnBv[j];
            float s = y / (1.0f + __expf(-y));
            out[ob + (size_t)(coutD + j) * HWS + pix] = s;
        }
    }
}

// ---------------------------------------------------------------------------
extern "C" void kernel_launch(void* const* d_in, const int* in_sizes, int n_in,
                              void* d_out, int out_size, void* d_ws, size_t ws_size,
                              hipStream_t stream) {
    const float* x        = (const float*)d_in[0];
    const float* offset_w = (const float*)d_in[1];
    const float* offset_b = (const float*)d_in[2];
    const float* mask_w   = (const float*)d_in[3];
    const float* mask_b   = (const float*)d_in[4];
    const float* conv_w   = (const float*)d_in[5];
    const float* bn_gamma = (const float*)d_in[6];
    const float* bn_beta  = (const float*)d_in[7];
    const float* bn_mean  = (const float*)d_in[8];
    const float* bn_var   = (const float*)d_in[9];

    char* ws = (char*)d_ws;
    size_t off = 0;
    ushort_t* xT   = (ushort_t*)(ws + off); off += (size_t)BB * HW * CC * 2;   // 13.1 MB
    float*    offs = (float*)(ws + off);    off += (size_t)BB * HW * 12 * 4;   //  4.9 MB
    ushort_t* cwBf = (ushort_t*)(ws + off); off += 64 * 64 * 2;
    float*    wmat = (float*)(ws + off);    off += 12 * 64 * 4;
    float*    wbias= (float*)(ws + off);    off += 64;
    float*    bnA  = (float*)(ws + off);    off += 64 * 4;
    float*    bnB  = (float*)(ws + off);    off += 64 * 4;

    prep_params<<<1, 256, 0, stream>>>(offset_w, offset_b, mask_w, mask_b, conv_w,
                                       bn_gamma, bn_beta, bn_mean, bn_var,
                                       wmat, wbias, cwBf, bnA, bnB);
    prep_x<<<BB * (HW / 64), 256, 0, stream>>>(x, wmat, wbias, xT, offs);
    dysample_main<<<dim3(HWS / 64, BB), 256, 0, stream>>>(xT, offs, cwBf, bnA, bnB,
                                                          (float*)d_out);
}